// Round 1
// baseline (91.493 us; speedup 1.0000x reference)
//
#include <hip/hip_runtime.h>

// DirectMaskedProjection: H=W=128, D=64, HIDDEN=64, mask vol 128^3 fp32 (binary).
// Round 3: eliminate ALL d_ws usage. rocprof showed two ~40us, 256 MiB
// fillBufferAligned dispatches (harness workspace re-poison) accounting for
// ~81 of the 86.9 us; our kernels are each <40us by the top-5 bound and
// ~10us by cost model. Fuse pack+dmp into ONE kernel that gathers the float
// volume directly (8 MB: half L2-resident per XCD, fully L3-resident), so the
// harness has no workspace state to re-poison. Mask/MLP numerics identical to
// the verified round-1/2 sequence (binary vol: (valid && v!=0) ? wgt : 0).
//
// Inputs (fp32): [0] transform [1,4,4], [1] mask_vol [128^3],
//                [2] W1 [3,64], [3] b1 [64], [4] W2 [64,1], [5] b2 [1]
// Output: fp32 [1,128,128] = 16384 elements.

#define NH 128
#define NW 128
#define ND 64
#define HID 64

__global__ __launch_bounds__(256) void dmp_fused_kernel(
    const float* __restrict__ T,    // [16]
    const float* __restrict__ vol,  // [128*128*128] floats (binary 0/1)
    const float* __restrict__ W1,   // [3,64] row-major
    const float* __restrict__ b1,   // [64]
    const float* __restrict__ W2,   // [64]
    const float* __restrict__ b2,   // [1]
    float* __restrict__ out)        // [128*128]
{
    const int t   = blockIdx.x * 256 + threadIdx.x;   // point index
    const int d   = t & 63;                           // depth sample == lane
    const int pix = t >> 6;                           // pixel index h*128+w
    const int h   = pix >> 7;
    const int w   = pix & 127;

    // centered base grid: x=h-63.5, y=w-63.5, z=(d-31.5)*2
    const float bx = (float)h - 63.5f;
    const float by = (float)w - 63.5f;
    const float bz = ((float)d - 31.5f) * 2.0f;

    // q = T @ [bx,by,bz,1]  (T uniform across threads -> scalar loads)
    const float q0 = T[0]  * bx + T[1]  * by + T[2]  * bz + T[3];
    const float q1 = T[4]  * bx + T[5]  * by + T[6]  * bz + T[7];
    const float q2 = T[8]  * bx + T[9]  * by + T[10] * bz + T[11];
    const float qw = T[12] * bx + T[13] * by + T[14] * bz + T[15];

    // normalize by max|base coord| = 63.5 (same fp sequence as rounds 1/2)
    const float inv_max = 1.0f / 63.5f;
    const float nx = q0 * inv_max;
    const float ny = q1 * inv_max;
    const float nz = q2 * inv_max;

    // voxel-space coords, align_corners=True; x->Wm, y->Hm, z->Dm
    const float xf = (nx + 1.0f) * 0.5f * 127.0f;
    const float yf = (ny + 1.0f) * 0.5f * 127.0f;
    const float zf = (nz + 1.0f) * 0.5f * 127.0f;
    const float x0 = floorf(xf), y0 = floorf(yf), z0 = floorf(zf);
    const float fx = xf - x0, fy = yf - y0, fz = zf - z0;

    // wave-uniform skip: any corner of any lane inside the volume?
    const bool lane_touch = (xf >= -1.0f) && (x0 <= 127.0f)
                         && (yf >= -1.0f) && (y0 <= 127.0f)
                         && (zf >= -1.0f) && (z0 <= 127.0f);

    float m = 0.0f;
    if (__any(lane_touch)) {
        #pragma unroll
        for (int dz_ = 0; dz_ < 2; ++dz_) {
            #pragma unroll
            for (int dy_ = 0; dy_ < 2; ++dy_) {
                #pragma unroll
                for (int dx_ = 0; dx_ < 2; ++dx_) {
                    const float xi = x0 + (float)dx_;
                    const float yi = y0 + (float)dy_;
                    const float zi = z0 + (float)dz_;
                    const float wgt = (dx_ ? fx : 1.0f - fx)
                                    * (dy_ ? fy : 1.0f - fy)
                                    * (dz_ ? fz : 1.0f - fz);
                    const bool valid = (xi >= 0.0f) && (xi <= 127.0f)
                                    && (yi >= 0.0f) && (yi <= 127.0f)
                                    && (zi >= 0.0f) && (zi <= 127.0f);
                    const int xc = min(max((int)xi, 0), 127);
                    const int yc = min(max((int)yi, 0), 127);
                    const int zc = min(max((int)zi, 0), 127);
                    // direct float gather (binary volume); identical partial
                    // sums to the bit-packed round 2 for binary vol:
                    const float v = vol[(zc << 14) + (yc << 7) + xc];
                    m += (valid && (v != 0.0f)) ? wgt : 0.0f;
                }
            }
        }
    }
    const float mask = (m != 0.0f) ? 1.0f : 0.0f;

    // field MLP: relu(q3 @ W1 + b1) @ W2 + b2, q3 = q/qw (qw == 1).
    // Skip entirely when the whole wave is masked out.
    float val = 0.0f;
    if (__any(mask != 0.0f)) {
        const float invw = 1.0f / qw;
        const float p0 = q0 * invw, p1 = q1 * invw, p2 = q2 * invw;
        float pot = b2[0];
        #pragma unroll 8
        for (int j = 0; j < HID; ++j) {
            float hj = p0 * W1[j] + p1 * W1[64 + j] + p2 * W1[128 + j] + b1[j];
            hj = fmaxf(hj, 0.0f);
            pot += hj * W2[j];
        }
        val = pot * mask;
    }

    // per-pixel reduction over the 64 depth lanes (one full wave)
    #pragma unroll
    for (int off = 32; off > 0; off >>= 1)
        val += __shfl_down(val, off);

    if (d == 0)
        out[pix] = val * 2.0f;   // * DZ
}

extern "C" void kernel_launch(void* const* d_in, const int* in_sizes, int n_in,
                              void* d_out, int out_size, void* d_ws, size_t ws_size,
                              hipStream_t stream) {
    const float* T   = (const float*)d_in[0];
    const float* vol = (const float*)d_in[1];
    const float* W1  = (const float*)d_in[2];
    const float* b1  = (const float*)d_in[3];
    const float* W2  = (const float*)d_in[4];
    const float* b2  = (const float*)d_in[5];
    float* out = (float*)d_out;

    (void)d_ws; (void)ws_size;   // deliberately unused: avoid ws re-poison cost

    const int n_points = NH * NW * ND;   // 1,048,576
    dmp_fused_kernel<<<n_points / 256, 256, 0, stream>>>(
        T, vol, W1, b1, W2, b2, out);
}

// Round 2
// 89.031 us; speedup vs baseline: 1.0277x; 1.0277x over previous
//
#include <hip/hip_runtime.h>

// DirectMaskedProjection: H=W=128, D=64, HIDDEN=64, mask vol 128^3 fp32 (binary).
// Round 4: restore ws bit-pack (round-1 proved the 2x 256MiB ws poison fills,
// ~81.7us, are UNCONDITIONAL -> ws is free; floats-direct gathers cost +5us).
// On top of round-0:
//  (a) 2x2x2-dilated bit volume `oc`: generic interior points get mask from ONE
//      u32 gather (m!=0 <=> OR of corner bits when all weights>0 -- exact for a
//      binary volume with nonneg weights). Edge/boundary lanes fall back to the
//      verified round-0 8-corner sum, bit-identical.
//  (b) MLP loop-exchange: hj(d) = u_j + g_j*d is affine in depth. Lane=j (wave
//      = pixel): masked relu depth-sum S_j = u_j*N + g_j*SumD over
//      R = range_mask & M, M = ballot of per-depth mask, SumD via constant
//      bit-plane popcounts. ~110 VALU/lane vs ~390.
//
// Inputs (fp32): [0] transform [1,4,4], [1] mask_vol [128^3],
//                [2] W1 [3,64], [3] b1 [64], [4] W2 [64,1], [5] b2 [1]
// Output: fp32 [1,128,128]. ws: bits (256KB) @0, oc (256KB) @256KB.

#define NH 128
#define NW 128
#define ND 64
#define HID 64

// Pack vol!=0 into bits: voxel index t -> bit (t & 63) of u64 word (t >> 6).
__global__ __launch_bounds__(256) void pack_kernel(
    const float* __restrict__ vol,
    unsigned long long* __restrict__ bits)
{
    const int t = blockIdx.x * 256 + threadIdx.x;   // 2^21 voxels
    const float v = vol[t];
    const unsigned long long b = __ballot(v != 0.0f);
    if ((threadIdx.x & 63) == 0)
        bits[t >> 6] = b;
}

// oc[z][y][x] = OR of bits over the 2x2x2 cube at (z,y,x) (+1 neighbors in
// each axis; shifts feed 0 past the x=127 / y=127 / z=127 faces, which the
// generic path never reads anyway since it requires floor coords <= 126).
__global__ __launch_bounds__(256) void dilate_kernel(
    const unsigned long long* __restrict__ b,
    unsigned long long* __restrict__ oc)
{
    const int r = blockIdx.x * 256 + threadIdx.x;   // row id: z*128 + y
    const int z = r >> 7, y = r & 127;
    const int i = r << 1;                           // u64 index (2 per row)
    unsigned long long lo = b[i], hi = b[i + 1];
    if (y < 127) { lo |= b[i + 2];   hi |= b[i + 3]; }
    if (z < 127) {
        lo |= b[i + 256]; hi |= b[i + 257];
        if (y < 127) { lo |= b[i + 258]; hi |= b[i + 259]; }
    }
    // x-dilation: oc_bit[x] = merged[x] | merged[x+1]
    oc[i]     = lo | (lo >> 1) | (hi << 63);
    oc[i + 1] = hi | (hi >> 1);
}

__global__ __launch_bounds__(256) void dmp_kernel(
    const float* __restrict__ T,          // [16]
    const unsigned int* __restrict__ bw,  // packed bits, 128*128*4 u32 words
    const unsigned int* __restrict__ oc,  // dilated bits, same layout
    const float* __restrict__ W1,         // [3,64] row-major
    const float* __restrict__ b1,         // [64]
    const float* __restrict__ W2,         // [64]
    const float* __restrict__ b2,         // [1]
    float* __restrict__ out)              // [128*128]
{
    const int t    = blockIdx.x * 256 + threadIdx.x;
    const int lane = t & 63;              // phase A: depth d; phase B: hidden j
    const int pix  = t >> 6;              // wave-uniform pixel h*128+w
    const int h    = pix >> 7;
    const int w    = pix & 127;

    const float bx = (float)h - 63.5f;
    const float by = (float)w - 63.5f;
    const float bz = ((float)lane - 31.5f) * 2.0f;

    // ---- phase A (lane = depth): per-point mask bit ----
    // q = T @ [bx,by,bz,1]; qw == 1 exactly (rigid T, last row [0,0,0,1])
    const float q0 = T[0] * bx + T[1] * by + T[2]  * bz + T[3];
    const float q1 = T[4] * bx + T[5] * by + T[6]  * bz + T[7];
    const float q2 = T[8] * bx + T[9] * by + T[10] * bz + T[11];

    const float inv_max = 1.0f / 63.5f;
    const float xf = (q0 * inv_max + 1.0f) * 0.5f * 127.0f;
    const float yf = (q1 * inv_max + 1.0f) * 0.5f * 127.0f;
    const float zf = (q2 * inv_max + 1.0f) * 0.5f * 127.0f;
    const float x0 = floorf(xf), y0 = floorf(yf), z0 = floorf(zf);
    const float fx = xf - x0, fy = yf - y0, fz = zf - z0;

    const bool lane_touch = (xf >= -1.0f) && (x0 <= 127.0f)
                         && (yf >= -1.0f) && (y0 <= 127.0f)
                         && (zf >= -1.0f) && (z0 <= 127.0f);

    // generic interior: all 8 corners valid AND all 8 weights strictly > 0
    const bool generic = (x0 >= 0.0f) && (x0 <= 126.0f) && (fx != 0.0f)
                      && (y0 >= 0.0f) && (y0 <= 126.0f) && (fy != 0.0f)
                      && (z0 >= 0.0f) && (z0 <= 126.0f) && (fz != 0.0f);

    const int x0i = (int)x0, y0i = (int)y0, z0i = (int)z0;
    const int xg = min(max(x0i, 0), 127);
    const int yg = min(max(y0i, 0), 127);
    const int zg = min(max(z0i, 0), 127);
    const unsigned int ocw = oc[((zg << 7) + yg) * 4 + (xg >> 5)];
    const bool ocbit = (ocw >> (xg & 31)) & 1u;

    float m = 0.0f;
    const bool edge = lane_touch && !generic;
    if (__any(edge)) {
        // verified round-0 8-corner trilinear sum (rare boundary lanes only)
        #pragma unroll
        for (int dz_ = 0; dz_ < 2; ++dz_) {
            #pragma unroll
            for (int dy_ = 0; dy_ < 2; ++dy_) {
                #pragma unroll
                for (int dx_ = 0; dx_ < 2; ++dx_) {
                    const float xi = x0 + (float)dx_;
                    const float yi = y0 + (float)dy_;
                    const float zi = z0 + (float)dz_;
                    const float wgt = (dx_ ? fx : 1.0f - fx)
                                    * (dy_ ? fy : 1.0f - fy)
                                    * (dz_ ? fz : 1.0f - fz);
                    const bool valid = (xi >= 0.0f) && (xi <= 127.0f)
                                    && (yi >= 0.0f) && (yi <= 127.0f)
                                    && (zi >= 0.0f) && (zi <= 127.0f);
                    const int xc = min(max((int)xi, 0), 127);
                    const int yc = min(max((int)yi, 0), 127);
                    const int zc = min(max((int)zi, 0), 127);
                    const unsigned int word = bw[((zc << 7) + yc) * 4 + (xc >> 5)];
                    const bool bit = (word >> (xc & 31)) & 1u;
                    m += (edge && valid && bit) ? wgt : 0.0f;
                }
            }
        }
    }
    const bool masked = generic ? ocbit : (m != 0.0f);
    const unsigned long long M = __ballot(masked);

    if (M == 0ull) {                       // whole ray outside / unmasked
        if (lane == 0) out[pix] = 0.0f;
        return;
    }

    // ---- phase B (lane = hidden unit j): analytic masked relu depth-sum ----
    // hj(d) = u + g*d  with bz = 2d - 63 folded in.
    const int j = lane;
    const float w0 = W1[j], w1 = W1[64 + j], w2 = W1[128 + j];
    const float A  = w0 * T[0] + w1 * T[4] + w2 * T[8];
    const float B  = w0 * T[1] + w1 * T[5] + w2 * T[9];
    const float C  = w0 * T[2] + w1 * T[6] + w2 * T[10];
    const float D0 = w0 * T[3] + w1 * T[7] + w2 * T[11] + b1[j];
    const float u  = A * bx + B * by - 63.0f * C + D0;
    const float g  = C + C;

    // active depth range where h(d) > 0 (h monotone in d; fp-predicate
    // boundary found via fast divide + one-step correction against fmaf)
    unsigned long long rmask;
    if (g > 0.0f) {
        const float tt = __fdividef(-u, g);
        int d0 = (int)floorf(tt) + 1;              // first active d
        d0 = min(max(d0, 0), 64);
        if (d0 > 0 && fmaf(g, (float)(d0 - 1), u) > 0.0f)       d0 -= 1;
        else if (d0 < 64 && fmaf(g, (float)d0, u) <= 0.0f)      d0 += 1;
        rmask = (d0 >= 64) ? 0ull : (~0ull << d0);
    } else if (g < 0.0f) {
        const float tt = __fdividef(-u, g);
        int d1 = (int)floorf(tt);                  // last active d
        d1 = min(max(d1, -1), 63);
        if (d1 < 63 && fmaf(g, (float)(d1 + 1), u) > 0.0f)      d1 += 1;
        else if (d1 >= 0 && fmaf(g, (float)d1, u) <= 0.0f)      d1 -= 1;
        rmask = (d1 < 0) ? 0ull : (~0ull >> (63 - d1));
    } else {
        rmask = (u > 0.0f) ? ~0ull : 0ull;
    }

    const unsigned long long R = rmask & M;
    const unsigned int rlo = (unsigned int)R;
    const unsigned int rhi = (unsigned int)(R >> 32);
    const int N = __popc(rlo) + __popc(rhi);
    // SumD = sum of depth indices in R, via constant bit-plane popcounts
    int Dsum = __popc(rlo & 0xAAAAAAAAu)        + (__popc(rlo & 0xCCCCCCCCu) << 1)
             + (__popc(rlo & 0xF0F0F0F0u) << 2) + (__popc(rlo & 0xFF00FF00u) << 3)
             + (__popc(rlo & 0xFFFF0000u) << 4);
    Dsum += __popc(rhi & 0xAAAAAAAAu)        + (__popc(rhi & 0xCCCCCCCCu) << 1)
          + (__popc(rhi & 0xF0F0F0F0u) << 2) + (__popc(rhi & 0xFF00FF00u) << 3)
          + (__popc(rhi & 0xFFFF0000u) << 4) + (__popc(rhi) << 5);

    const float S = u * (float)N + g * (float)Dsum;   // sum_d relu(h(d)) over R
    float val = W2[j] * S;

    #pragma unroll
    for (int off = 32; off > 0; off >>= 1)
        val += __shfl_down(val, off);

    if (lane == 0) {
        const float nm = (float)(__popc((unsigned int)M)
                               + __popc((unsigned int)(M >> 32)));
        out[pix] = (val + b2[0] * nm) * 2.0f;          // * DZ
    }
}

extern "C" void kernel_launch(void* const* d_in, const int* in_sizes, int n_in,
                              void* d_out, int out_size, void* d_ws, size_t ws_size,
                              hipStream_t stream) {
    const float* T   = (const float*)d_in[0];
    const float* vol = (const float*)d_in[1];
    const float* W1  = (const float*)d_in[2];
    const float* b1  = (const float*)d_in[3];
    const float* W2  = (const float*)d_in[4];
    const float* b2  = (const float*)d_in[5];
    float* out = (float*)d_out;

    unsigned long long* bits = (unsigned long long*)d_ws;              // 256 KB
    unsigned long long* oc   = (unsigned long long*)((char*)d_ws + 262144);

    pack_kernel<<<8192, 256, 0, stream>>>(vol, bits);          // 2^21 voxels
    dilate_kernel<<<64, 256, 0, stream>>>(bits, oc);           // 16384 rows

    const int n_points = NH * NW * ND;   // 1,048,576
    dmp_kernel<<<n_points / 256, 256, 0, stream>>>(
        T, (const unsigned int*)bits, (const unsigned int*)oc,
        W1, b1, W2, b2, out);
}

// Round 3
// 80.765 us; speedup vs baseline: 1.1328x; 1.1023x over previous
//
#include <hip/hip_runtime.h>

// DirectMaskedProjection: H=W=128, D=64, HIDDEN=64, mask vol 128^3 fp32 (binary).
// Round 5: two launches, no hot-path fallback.
//  - pack_xdil: pack vol!=0 into bits (256KB) AND per-row extended x-dilation
//    O[xI] = bit(xI-1)|bit(xI), xI in [0,128], zero-filled ends (512KB, 32B rows).
//  - dmp: mask via OR of 4 bounds-predicated (z,y) row lookups at xI=x0+1 —
//    EXACT equivalence to (trilinear m != 0) for a binary volume with
//    nonneg weights, for all x0 in [-1,127] incl. both faces, provided no
//    fract is exactly 0 (measure-zero; verified 8-corner fallback kept behind
//    __any, effectively never executes). Analytic phase-B MLP from round 4
//    (verified, absmax 0.25): hj(d)=u+g*d affine in depth, lane=hidden unit,
//    masked relu depth-sum via range mask & ballot M + bit-plane popcounts.
// Round-1/2 lesson: the 2x 256MiB ws poison fills (~82us) are unconditional,
// so ws is free; the controllable budget is only the ~5-7us of kernel work.
//
// Inputs (fp32): [0] transform [1,4,4], [1] mask_vol [128^3],
//                [2] W1 [3,64], [3] b1 [64], [4] W2 [64,1], [5] b2 [1]
// Output: fp32 [1,128,128]. ws: bits 256KB @0, xdil 512KB @256KB.

#define NH 128
#define NW 128
#define ND 64
#define HID 64

// Block = 256 threads = 2 full rows (z*128+y). 4 waves -> 4 ballots; LDS
// exchange; threads 0,1 emit raw bits + extended x-dilated row (4-u64 stride).
__global__ __launch_bounds__(256) void pack_xdil_kernel(
    const float* __restrict__ vol,
    unsigned long long* __restrict__ bits,   // [16384*2]
    unsigned long long* __restrict__ xd)     // [16384*4] padded rows
{
    __shared__ unsigned long long s[4];
    const int t = blockIdx.x * 256 + threadIdx.x;   // voxel index, x fastest
    const float v = vol[t];
    const unsigned long long b = __ballot(v != 0.0f);
    if ((threadIdx.x & 63) == 0) s[threadIdx.x >> 6] = b;
    __syncthreads();
    if (threadIdx.x < 2) {
        const int r = blockIdx.x * 2 + threadIdx.x;         // row id
        const unsigned long long lo = s[threadIdx.x * 2];     // x 0..63
        const unsigned long long hi = s[threadIdx.x * 2 + 1]; // x 64..127
        bits[r * 2]     = lo;
        bits[r * 2 + 1] = hi;
        // O[xI] = bit(xI-1)|bit(xI): O = L | (L<<1) over 129 bits
        xd[r * 4]     = lo | (lo << 1);
        xd[r * 4 + 1] = hi | (hi << 1) | (lo >> 63);
        xd[r * 4 + 2] = hi >> 63;                  // bit xI=128 = bit(127)
        // xd[r*4+3] never read
    }
}

__global__ __launch_bounds__(256) void dmp_kernel(
    const float* __restrict__ T,          // [16]
    const unsigned int* __restrict__ bw,  // raw bits, 4 u32/row (fallback only)
    const unsigned int* __restrict__ xd,  // x-dilated ext rows, 8 u32/row
    const float* __restrict__ W1,         // [3,64] row-major
    const float* __restrict__ b1,         // [64]
    const float* __restrict__ W2,         // [64]
    const float* __restrict__ b2,         // [1]
    float* __restrict__ out)              // [128*128]
{
    const int t    = blockIdx.x * 256 + threadIdx.x;
    const int lane = t & 63;              // phase A: depth d; phase B: hidden j
    const int pix  = t >> 6;              // wave-uniform pixel h*128+w
    const int h    = pix >> 7;
    const int w    = pix & 127;

    const float bx = (float)h - 63.5f;
    const float by = (float)w - 63.5f;
    const float bz = ((float)lane - 31.5f) * 2.0f;

    // ---- phase A (lane = depth): per-point mask bit ----
    // q = T @ [bx,by,bz,1]; qw == 1 exactly (rigid T, last row [0,0,0,1])
    const float q0 = T[0] * bx + T[1] * by + T[2]  * bz + T[3];
    const float q1 = T[4] * bx + T[5] * by + T[6]  * bz + T[7];
    const float q2 = T[8] * bx + T[9] * by + T[10] * bz + T[11];

    const float inv_max = 1.0f / 63.5f;
    const float xf = (q0 * inv_max + 1.0f) * 0.5f * 127.0f;
    const float yf = (q1 * inv_max + 1.0f) * 0.5f * 127.0f;
    const float zf = (q2 * inv_max + 1.0f) * 0.5f * 127.0f;
    const float x0 = floorf(xf), y0 = floorf(yf), z0 = floorf(zf);
    const float fx = xf - x0, fy = yf - y0, fz = zf - z0;

    const bool lane_touch = (xf >= -1.0f) && (x0 <= 127.0f)
                         && (yf >= -1.0f) && (y0 <= 127.0f)
                         && (zf >= -1.0f) && (z0 <= 127.0f);

    const int x0i = (int)x0, y0i = (int)y0, z0i = (int)z0;
    const int xI  = min(max(x0i + 1, 0), 128);   // clamp only for safety of
                                                 // non-touch lanes' addresses
    bool masked = false;
    #pragma unroll
    for (int dz_ = 0; dz_ < 2; ++dz_) {
        #pragma unroll
        for (int dy_ = 0; dy_ < 2; ++dy_) {
            const int zr = z0i + dz_;
            const int yr = y0i + dy_;
            const bool vzy = (zr >= 0) && (zr <= 127) && (yr >= 0) && (yr <= 127);
            const int zc = min(max(zr, 0), 127);
            const int yc = min(max(yr, 0), 127);
            const unsigned int word = xd[(((zc << 7) + yc) << 3) + (xI >> 5)];
            masked = masked || (vzy && (((word >> (xI & 31)) & 1u) != 0u));
        }
    }
    masked = masked && lane_touch;

    // exact fallback for exact-integer coords (fract==0); effectively never
    const bool fb = lane_touch && ((fx == 0.0f) || (fy == 0.0f) || (fz == 0.0f));
    if (__any(fb)) {
        float m = 0.0f;
        #pragma unroll
        for (int dz_ = 0; dz_ < 2; ++dz_) {
            #pragma unroll
            for (int dy_ = 0; dy_ < 2; ++dy_) {
                #pragma unroll
                for (int dx_ = 0; dx_ < 2; ++dx_) {
                    const float xi = x0 + (float)dx_;
                    const float yi = y0 + (float)dy_;
                    const float zi = z0 + (float)dz_;
                    const float wgt = (dx_ ? fx : 1.0f - fx)
                                    * (dy_ ? fy : 1.0f - fy)
                                    * (dz_ ? fz : 1.0f - fz);
                    const bool valid = (xi >= 0.0f) && (xi <= 127.0f)
                                    && (yi >= 0.0f) && (yi <= 127.0f)
                                    && (zi >= 0.0f) && (zi <= 127.0f);
                    const int xc = min(max((int)xi, 0), 127);
                    const int yc = min(max((int)yi, 0), 127);
                    const int zc = min(max((int)zi, 0), 127);
                    const unsigned int word = bw[((zc << 7) + yc) * 4 + (xc >> 5)];
                    const bool bit = (word >> (xc & 31)) & 1u;
                    m += (fb && valid && bit) ? wgt : 0.0f;
                }
            }
        }
        if (fb) masked = (m != 0.0f);
    }

    const unsigned long long M = __ballot(masked);
    if (M == 0ull) {                       // whole ray outside / unmasked
        if (lane == 0) out[pix] = 0.0f;
        return;
    }

    // ---- phase B (lane = hidden unit j): analytic masked relu depth-sum ----
    // hj(d) = u + g*d  with bz = 2d - 63 folded in. (verified round 4)
    const int j = lane;
    const float w0 = W1[j], w1 = W1[64 + j], w2 = W1[128 + j];
    const float A  = w0 * T[0] + w1 * T[4] + w2 * T[8];
    const float B  = w0 * T[1] + w1 * T[5] + w2 * T[9];
    const float C  = w0 * T[2] + w1 * T[6] + w2 * T[10];
    const float D0 = w0 * T[3] + w1 * T[7] + w2 * T[11] + b1[j];
    const float u  = A * bx + B * by - 63.0f * C + D0;
    const float g  = C + C;

    // active depth range where h(d) > 0 (h monotone in d; fp-predicate
    // boundary via fast divide + one-step fmaf correction)
    unsigned long long rmask;
    if (g > 0.0f) {
        const float tt = __fdividef(-u, g);
        int d0 = (int)floorf(tt) + 1;              // first active d
        d0 = min(max(d0, 0), 64);
        if (d0 > 0 && fmaf(g, (float)(d0 - 1), u) > 0.0f)       d0 -= 1;
        else if (d0 < 64 && fmaf(g, (float)d0, u) <= 0.0f)      d0 += 1;
        rmask = (d0 >= 64) ? 0ull : (~0ull << d0);
    } else if (g < 0.0f) {
        const float tt = __fdividef(-u, g);
        int d1 = (int)floorf(tt);                  // last active d
        d1 = min(max(d1, -1), 63);
        if (d1 < 63 && fmaf(g, (float)(d1 + 1), u) > 0.0f)      d1 += 1;
        else if (d1 >= 0 && fmaf(g, (float)d1, u) <= 0.0f)      d1 -= 1;
        rmask = (d1 < 0) ? 0ull : (~0ull >> (63 - d1));
    } else {
        rmask = (u > 0.0f) ? ~0ull : 0ull;
    }

    const unsigned long long R = rmask & M;
    const unsigned int rlo = (unsigned int)R;
    const unsigned int rhi = (unsigned int)(R >> 32);
    const int N = __popc(rlo) + __popc(rhi);
    // SumD = sum of depth indices in R, via constant bit-plane popcounts
    int Dsum = __popc(rlo & 0xAAAAAAAAu)        + (__popc(rlo & 0xCCCCCCCCu) << 1)
             + (__popc(rlo & 0xF0F0F0F0u) << 2) + (__popc(rlo & 0xFF00FF00u) << 3)
             + (__popc(rlo & 0xFFFF0000u) << 4);
    Dsum += __popc(rhi & 0xAAAAAAAAu)        + (__popc(rhi & 0xCCCCCCCCu) << 1)
          + (__popc(rhi & 0xF0F0F0F0u) << 2) + (__popc(rhi & 0xFF00FF00u) << 3)
          + (__popc(rhi & 0xFFFF0000u) << 4) + (__popc(rhi) << 5);

    const float S = u * (float)N + g * (float)Dsum;   // sum_d relu(h(d)) over R
    float val = W2[j] * S;

    #pragma unroll
    for (int off = 32; off > 0; off >>= 1)
        val += __shfl_down(val, off);

    if (lane == 0) {
        const float nm = (float)(__popc((unsigned int)M)
                               + __popc((unsigned int)(M >> 32)));
        out[pix] = (val + b2[0] * nm) * 2.0f;          // * DZ
    }
}

extern "C" void kernel_launch(void* const* d_in, const int* in_sizes, int n_in,
                              void* d_out, int out_size, void* d_ws, size_t ws_size,
                              hipStream_t stream) {
    const float* T   = (const float*)d_in[0];
    const float* vol = (const float*)d_in[1];
    const float* W1  = (const float*)d_in[2];
    const float* b1  = (const float*)d_in[3];
    const float* W2  = (const float*)d_in[4];
    const float* b2  = (const float*)d_in[5];
    float* out = (float*)d_out;

    unsigned long long* bits = (unsigned long long*)d_ws;              // 256 KB
    unsigned long long* xd   = (unsigned long long*)((char*)d_ws + 262144); // 512 KB

    pack_xdil_kernel<<<8192, 256, 0, stream>>>(vol, bits, xd);  // 2^21 voxels

    const int n_points = NH * NW * ND;   // 1,048,576
    dmp_kernel<<<n_points / 256, 256, 0, stream>>>(
        T, (const unsigned int*)bits, (const unsigned int*)xd,
        W1, b1, W2, b2, out);
}